// Round 8
// baseline (126.207 us; speedup 1.0000x reference)
//
#include <hip/hip_runtime.h>

#define B_N 32
#define LQ  1024
#define LK  1024
#define DH  128

typedef __attribute__((ext_vector_type(4))) float    f32x4;
typedef __attribute__((ext_vector_type(8))) short    s16x8;
typedef __attribute__((ext_vector_type(4))) _Float16 f16x4;
typedef __attribute__((ext_vector_type(8))) _Float16 f16x8;

// fp32 -> bf16 round-to-nearest-even
__device__ inline unsigned short f2bf(float f) {
    union { float f; unsigned u; } c; c.f = f;
    unsigned u = c.u;
    u += 0x7fffu + ((u >> 16) & 1u);
    return (unsigned short)(u >> 16);
}

// logit2 = score * (1/sqrt(128)) * log2(e)
#define ESCALE 0.12751743f

// async global->LDS, 16B per lane (dest must be wave-uniform base + lane*16)
#define G2L16(gp, lp) __builtin_amdgcn_global_load_lds(                         \
    (const __attribute__((address_space(1))) void*)(gp),                        \
    (__attribute__((address_space(3))) void*)(lp), 16, 0, 0)

// ---------------------------------------------------------------------------
// Prepass: byte-identical to r5 (grid 2048; UL list dropped — r7 proved the
// pairing null). XCD-aligned decode kept (neutral). vl-aware skip unchanged.
// blocks 0..1023: K tiles -> Kb bf16 fragments for QK^T (16x16x32).
// blocks 1024..2047: V tiles -> Vt f16 fragment-PAIRS for PV (16x16x16).
// ---------------------------------------------------------------------------
__global__ __launch_bounds__(256)
void prep_kv(const float* __restrict__ K, const float* __restrict__ V,
             const int* __restrict__ VL,
             unsigned short* __restrict__ Kb, _Float16* __restrict__ Vt)
{
    __shared__ float tl[32 * 132];
    const int tid  = threadIdx.x;
    const int lane = tid & 63;
    const int wv   = tid >> 6;
    const int n    = lane & 15;
    const int quad = lane >> 4;

    const int  idx = blockIdx.x;
    const bool isK = (idx >> 10) == 0;
    const int  b   = (idx & 7) | (((idx >> 3) & 3) << 3);
    const int  kt  = (idx >> 5) & 31;

    const int vl = VL[b];
    if (isK) {
        if (vl <= 0 || kt >= 2 * ((vl + 63) >> 6)) return;   // block-uniform
    } else {
        const int nch = (vl > 0) ? ((vl + 63) >> 6) : 16;
        if (kt >= 2 * nch) return;                           // block-uniform
    }

    const float4* src = (const float4*)((isK ? K : V) + ((size_t)b * LK + kt * 32) * DH);
    #pragma unroll
    for (int h = 0; h < 4; ++h) {
        const int i2 = h * 256 + tid;
        const int row = i2 >> 5, c4 = i2 & 31;
        *(float4*)&tl[row * 132 + c4 * 4] = src[i2];
    }
    __syncthreads();

    if (isK) {
        union { s16x8 v; unsigned short u[8]; } t8;
        #pragma unroll
        for (int h = 0; h < 2; ++h) {
            const int f = wv * 2 + h;
            const int tt2 = f >> 2, s = f & 3;
            const float* p = &tl[(tt2 * 16 + n) * 132 + s * 32 + quad * 8];
            const float4 a = *(const float4*)p;
            const float4 c = *(const float4*)(p + 4);
            t8.u[0] = f2bf(a.x); t8.u[1] = f2bf(a.y); t8.u[2] = f2bf(a.z); t8.u[3] = f2bf(a.w);
            t8.u[4] = f2bf(c.x); t8.u[5] = f2bf(c.y); t8.u[6] = f2bf(c.z); t8.u[7] = f2bf(c.w);
            const int w = b * 256 + (kt * 2 + tt2) * 4 + s;
            *(s16x8*)(Kb + (size_t)w * 512 + lane * 8) = t8.v;
        }
    } else {
        #pragma unroll
        for (int h = 0; h < 2; ++h) {
            const int f  = wv * 2 + h;
            const int kg = f >> 2, dp = f & 3;
            f16x8 t8;
            #pragma unroll
            for (int i = 0; i < 4; ++i) {
                const float* row = &tl[(kg * 16 + quad * 4 + i) * 132 + dp * 32 + n];
                t8[i]     = (_Float16)row[0];
                t8[4 + i] = (_Float16)row[16];
            }
            const int v = (b * 64 + kt * 2 + kg) * 4 + dp;
            *(f16x8*)(Vt + (size_t)v * 512 + lane * 8) = t8;
        }
    }
}

// ---------------------------------------------------------------------------
// Attention v8: intra-block wave-parity split-K (the round-8 change).
// r6/r7 post-mortem: balance is NOT the limiter (LPT and pairing both
// null/negative) -> chunks are throughput-bound on a per-CU shared pipe.
// The dominant pipe term in r5: LDS reads. ALL 4 waves read the full 32KB
// chunk (kf/w8 addresses are wave-independent): 128 ds_read_b128/instance
// x 12cy x 17 instances/CU ~ 11us. v8 halves it: wave (h2=wv>>1, j=wv&1)
// owns 32 q-rows (2 qtiles, r0's dual-MFMA-per-kf-read) and computes only
// chunks with t&1==j -> each datum read by 2 waves, 64 inst/instance.
// Staging UNCHANGED (all threads stage every chunk — avoids r6's doubled
// DMA); barriers unchanged (2/chunk, outside the parity guard: no barrier
// divergence); MFMA/exp2 totals invariant. End: r6's proven split-K merge
// over j through bufK/bufV (free after the loop: last iter did vmcnt(0)
// and no STAGE remains in flight). r4's trap avoided: 8 waves/CU resident
// (2 blocks x 4), cross-block phase offsets cover the half-idle phases.
// ~170 VGPR at 2 waves/SIMD (LDS-capped) — within the 256 budget.
// Pipeline (r5, kept): prologue stages chunks 0+1; per iter wait vmcnt(8)
// (chunk t landed, t+1 flying), barrier (a), compute-if-my-parity,
// barrier (b), STAGE(t+2) into the vacated buffer.
// Register rule: never index a register array with a runtime value (buf
// index t&1 is LDS memory, fine; all o/pA/qf indices compile-time).
// Transposed-S trick unchanged: S^T = K.Q^T C-layout == A-operand layout
// of 16x16x16 f16 MFMA -> exp2(S^T) feeds PV directly.
// ---------------------------------------------------------------------------
__global__ __launch_bounds__(256)
void attn_fwd(const float* __restrict__ Q, const unsigned short* __restrict__ Kb,
              const _Float16* __restrict__ Vt, const int* __restrict__ VL,
              float* __restrict__ O)
{
    __shared__ __align__(16) unsigned short bufK[2][16 * 512];  // 16 KB / buf
    __shared__ __align__(16) _Float16       bufV[2][16 * 512];  // 16 KB / buf

    const int tid  = threadIdx.x;
    const int lane = tid & 63;
    const int wv   = tid >> 6;
    const int h2   = wv >> 1;      // row-half: rows [h2*32, h2*32+32)
    const int j    = wv & 1;       // chunk parity this wave computes
    const int quad = lane >> 4;
    const int m16  = lane & 15;

    const int idx = blockIdx.x;
    const int qg  = (idx >> 5) & 15;
    const int b   = (idx & 7) | ((((idx >> 3) + (idx >> 8)) & 3) << 3);
    const int q0  = qg * 64;

    const int vl  = VL[b];
    const int nch = (vl > 0) ? ((vl + 63) >> 6) : 16;
    const float emaskval = (vl == 0) ? 1.0f : 0.0f;

    // Q fragments for this wave's TWO qtiles (B-operand of transposed QK^T)
    s16x8 qf[2][4];
    #pragma unroll
    for (int h = 0; h < 2; ++h) {
        const float* qrow = Q + ((size_t)b * LQ + q0 + h2 * 32 + h * 16 + m16) * DH + quad * 8;
        #pragma unroll
        for (int s = 0; s < 4; ++s) {
            const float4 a = *(const float4*)(qrow + s * 32);
            const float4 c = *(const float4*)(qrow + s * 32 + 4);
            union { s16x8 v; unsigned short u[8]; } t;
            t.u[0] = f2bf(a.x); t.u[1] = f2bf(a.y); t.u[2] = f2bf(a.z); t.u[3] = f2bf(a.w);
            t.u[4] = f2bf(c.x); t.u[5] = f2bf(c.y); t.u[6] = f2bf(c.z); t.u[7] = f2bf(c.w);
            qf[h][s] = t.v;
        }
    }

    f32x4 o[2][8];
    #pragma unroll
    for (int h = 0; h < 2; ++h)
        #pragma unroll
        for (int dt = 0; dt < 8; ++dt) o[h][dt] = (f32x4){0.f, 0.f, 0.f, 0.f};
    float lrun[2] = {0.f, 0.f};

    // chunk t occupies shorts [t*8192, (t+1)*8192) of this batch's Kb / Vt
    const unsigned short* kg0 = Kb + (size_t)b * (256 * 512);
    const _Float16*       vg0 = Vt + (size_t)b * (256 * 512);
    const int co = tid * 8;  // this thread's 16B slot within a 16KB chunk copy

    // STAGE(c, t): 8 x global_load_lds dwordx4 per thread (4 K + 4 V)
    //              = 8 vmcnt events per wave
#define STAGE(c, t)                                                             \
    do {                                                                        \
        const unsigned short* gk_ = kg0 + (size_t)(t) * 8192;                   \
        const _Float16*       gv_ = vg0 + (size_t)(t) * 8192;                   \
        _Pragma("unroll")                                                       \
        for (int it_ = 0; it_ < 4; ++it_)                                       \
            G2L16(gk_ + it_ * 2048 + co, &bufK[c][it_ * 2048 + co]);            \
        _Pragma("unroll")                                                       \
        for (int it_ = 0; it_ < 4; ++it_)                                       \
            G2L16(gv_ + it_ * 2048 + co, &bufV[c][it_ * 2048 + co]);            \
    } while (0)

    // prologue: stage chunks 0 and 1 (chunk 1 is always within the batch's
    // 16-chunk allocation; unused/poison bytes are never computed if nch==1)
    STAGE(0, 0);
    STAGE(1, 1);

    for (int t = 0; t < nch; ++t) {
        // wait for chunk t to land: only chunk t+1's 8 per-wave loads may
        // remain in flight. Last iteration: drain everything.
        if (t + 1 < nch) { asm volatile("s_waitcnt vmcnt(8)" ::: "memory"); }
        else             { asm volatile("s_waitcnt vmcnt(0)" ::: "memory"); }
        __builtin_amdgcn_sched_barrier(0);
        __builtin_amdgcn_s_barrier();          // (a) chunk t visible to all waves
        __builtin_amdgcn_sched_barrier(0);

        if ((t & 1) == j) {                    // wave-uniform parity guard
            const unsigned short* bk = &bufK[t & 1][0];
            const _Float16*       bv = &bufV[t & 1][0];
            const bool maskc = (t * 64 + 64 > vl);
            f16x4 pA[2][4];

            // ---- S^T = K Q^T per 16-kpos tile g; one kf read feeds BOTH
            //      qtiles (st0/st1); softmaxed immediately ----
            #pragma unroll
            for (int g = 0; g < 4; ++g) {
                f32x4 st0 = (f32x4){0.f, 0.f, 0.f, 0.f};
                f32x4 st1 = (f32x4){0.f, 0.f, 0.f, 0.f};
                #pragma unroll
                for (int s = 0; s < 4; ++s) {
                    const s16x8 kf = *(const s16x8*)(bk + (g * 4 + s) * 512 + lane * 8);
                    st0 = __builtin_amdgcn_mfma_f32_16x16x32_bf16(kf, qf[0][s], st0, 0, 0, 0);
                    st1 = __builtin_amdgcn_mfma_f32_16x16x32_bf16(kf, qf[1][s], st1, 0, 0, 0);
                }
                #pragma unroll
                for (int i = 0; i < 4; ++i) {
                    float e0 = __builtin_amdgcn_exp2f(st0[i] * ESCALE);
                    float e1 = __builtin_amdgcn_exp2f(st1[i] * ESCALE);
                    if (maskc && (t * 64 + g * 16 + quad * 4 + i >= vl)) { e0 = emaskval; e1 = emaskval; }
                    lrun[0] += e0; lrun[1] += e1;
                    pA[0][g][i] = (_Float16)e0;
                    pA[1][g][i] = (_Float16)e1;
                }
            }

            // ---- O += P V : one w8 read feeds FOUR MFMAs ----
            #pragma unroll
            for (int g = 0; g < 4; ++g) {
                #pragma unroll
                for (int dp = 0; dp < 4; ++dp) {
                    const f16x8 w8 = *(const f16x8*)(bv + (g * 4 + dp) * 512 + lane * 8);
                    const f16x4 lo = __builtin_shufflevector(w8, w8, 0, 1, 2, 3);
                    const f16x4 hi = __builtin_shufflevector(w8, w8, 4, 5, 6, 7);
                    o[0][dp * 2]     = __builtin_amdgcn_mfma_f32_16x16x16f16(pA[0][g], lo, o[0][dp * 2],     0, 0, 0);
                    o[0][dp * 2 + 1] = __builtin_amdgcn_mfma_f32_16x16x16f16(pA[0][g], hi, o[0][dp * 2 + 1], 0, 0, 0);
                    o[1][dp * 2]     = __builtin_amdgcn_mfma_f32_16x16x16f16(pA[1][g], lo, o[1][dp * 2],     0, 0, 0);
                    o[1][dp * 2 + 1] = __builtin_amdgcn_mfma_f32_16x16x16f16(pA[1][g], hi, o[1][dp * 2 + 1], 0, 0, 0);
                }
            }
        }

        __builtin_amdgcn_s_barrier();          // (b) all waves done with buf[t&1]
        __builtin_amdgcn_sched_barrier(0);
        if (t + 2 < nch) STAGE(t & 1, t + 2);  // overwrite the vacated buffer
    }
#undef STAGE

    // ---- split-K merge over parity j per row-half h2, through the freed
    //      LDS (last iter drained vmcnt(0); no STAGE in flight) ----
    f32x4* Om = (f32x4*)&bufK[0][0];   // [(h2*2+h)*8+dt][lane] — 32 KB
    float*  Lm = (float*)&bufV[0][0];  // [(h2*2+h)][lane]      — 1 KB
    if (j == 1) {
        #pragma unroll
        for (int h = 0; h < 2; ++h) {
            #pragma unroll
            for (int dt = 0; dt < 8; ++dt)
                Om[((h2 * 2 + h) * 8 + dt) * 64 + lane] = o[h][dt];
            Lm[(h2 * 2 + h) * 64 + lane] = lrun[h];
        }
    }
    __syncthreads();
    if (j == 0) {
        #pragma unroll
        for (int h = 0; h < 2; ++h) {
            f32x4 om[8];
            #pragma unroll
            for (int dt = 0; dt < 8; ++dt)
                om[dt] = o[h][dt] + Om[((h2 * 2 + h) * 8 + dt) * 64 + lane];
            float L = lrun[h] + Lm[(h2 * 2 + h) * 64 + lane];

            // L[qrow=m16] total across quads, then per-row 1/L via shfl
            L += __shfl_xor(L, 16);
            L += __shfl_xor(L, 32);
            const size_t obase = ((size_t)b * LQ + q0 + h2 * 32 + h * 16 + quad * 4) * DH + m16;
            #pragma unroll
            for (int r = 0; r < 4; ++r) {
                const float inv = 1.0f / __shfl(L, quad * 4 + r);
                #pragma unroll
                for (int dt = 0; dt < 8; ++dt)
                    O[obase + (size_t)r * DH + dt * 16] = om[dt][r] * inv;
            }
        }
    }
}

extern "C" void kernel_launch(void* const* d_in, const int* in_sizes, int n_in,
                              void* d_out, int out_size, void* d_ws, size_t ws_size,
                              hipStream_t stream) {
    const float* Q  = (const float*)d_in[0];
    const float* K  = (const float*)d_in[1];
    const float* V  = (const float*)d_in[2];
    const int*   VL = (const int*)d_in[3];
    float* O = (float*)d_out;
    (void)in_sizes; (void)n_in; (void)out_size; (void)ws_size;

    unsigned short* Kb = (unsigned short*)d_ws;                      // 8 MB K fragments
    _Float16*       Vt = (_Float16*)(Kb + (size_t)B_N * 256 * 512);  // 8 MB V frag-pairs

    prep_kv<<<dim3(2048), dim3(256), 0, stream>>>(K, V, VL, Kb, Vt);
    attn_fwd<<<dim3(B_N * (LQ / 64)), dim3(256), 0, stream>>>(Q, Kb, Vt, VL, O);
}

// Round 9
// 117.050 us; speedup vs baseline: 1.0782x; 1.0782x over previous
//
#include <hip/hip_runtime.h>

#define B_N 32
#define LQ  1024
#define LK  1024
#define DH  128

typedef __attribute__((ext_vector_type(4))) float    f32x4;
typedef __attribute__((ext_vector_type(8))) short    s16x8;
typedef __attribute__((ext_vector_type(4))) _Float16 f16x4;
typedef __attribute__((ext_vector_type(8))) _Float16 f16x8;

// fp32 -> bf16 round-to-nearest-even
__device__ inline unsigned short f2bf(float f) {
    union { float f; unsigned u; } c; c.f = f;
    unsigned u = c.u;
    u += 0x7fffu + ((u >> 16) & 1u);
    return (unsigned short)(u >> 16);
}

// logit2 = score * (1/sqrt(128)) * log2(e)
#define ESCALE 0.12751743f

// async global->LDS, 16B per lane (dest must be wave-uniform base + lane*16)
#define G2L16(gp, lp) __builtin_amdgcn_global_load_lds(                         \
    (const __attribute__((address_space(1))) void*)(gp),                        \
    (__attribute__((address_space(3))) void*)(lp), 16, 0, 0)

// ---------------------------------------------------------------------------
// Prepass. One change vs r5: V-skip widened to 128-kpos granularity
// (kt < 4*ceil(vl/128)) because attn v9 consumes V in 128-kpos chunks —
// every V fragment PV touches must be real (P=0 x poison-inf = NaN).
// K-skip stays 64-granular: K poison only reaches exp2 and is overridden
// by the mask before any use (same guarantee as the vl==0 path).
// blocks 0..1023: K tiles -> Kb bf16 fragments for QK^T (16x16x32).
// blocks 1024..2047: V tiles -> Vt f16 fragment-PAIRS for PV (16x16x16).
// ---------------------------------------------------------------------------
__global__ __launch_bounds__(256)
void prep_kv(const float* __restrict__ K, const float* __restrict__ V,
             const int* __restrict__ VL,
             unsigned short* __restrict__ Kb, _Float16* __restrict__ Vt)
{
    __shared__ float tl[32 * 132];
    const int tid  = threadIdx.x;
    const int lane = tid & 63;
    const int wv   = tid >> 6;
    const int n    = lane & 15;
    const int quad = lane >> 4;

    const int  idx = blockIdx.x;
    const bool isK = (idx >> 10) == 0;
    const int  b   = (idx & 7) | (((idx >> 3) & 3) << 3);
    const int  kt  = (idx >> 5) & 31;

    const int vl = VL[b];
    if (isK) {
        if (vl <= 0 || kt >= 2 * ((vl + 63) >> 6)) return;   // block-uniform
    } else {
        const int vlim = (vl > 0) ? 4 * ((vl + 127) >> 7) : 32;
        if (kt >= vlim) return;                              // block-uniform
    }

    const float4* src = (const float4*)((isK ? K : V) + ((size_t)b * LK + kt * 32) * DH);
    #pragma unroll
    for (int h = 0; h < 4; ++h) {
        const int i2 = h * 256 + tid;
        const int row = i2 >> 5, c4 = i2 & 31;
        *(float4*)&tl[row * 132 + c4 * 4] = src[i2];
    }
    __syncthreads();

    if (isK) {
        union { s16x8 v; unsigned short u[8]; } t8;
        #pragma unroll
        for (int h = 0; h < 2; ++h) {
            const int f = wv * 2 + h;
            const int tt2 = f >> 2, s = f & 3;
            const float* p = &tl[(tt2 * 16 + n) * 132 + s * 32 + quad * 8];
            const float4 a = *(const float4*)p;
            const float4 c = *(const float4*)(p + 4);
            t8.u[0] = f2bf(a.x); t8.u[1] = f2bf(a.y); t8.u[2] = f2bf(a.z); t8.u[3] = f2bf(a.w);
            t8.u[4] = f2bf(c.x); t8.u[5] = f2bf(c.y); t8.u[6] = f2bf(c.z); t8.u[7] = f2bf(c.w);
            const int w = b * 256 + (kt * 2 + tt2) * 4 + s;
            *(s16x8*)(Kb + (size_t)w * 512 + lane * 8) = t8.v;
        }
    } else {
        #pragma unroll
        for (int h = 0; h < 2; ++h) {
            const int f  = wv * 2 + h;
            const int kg = f >> 2, dp = f & 3;
            f16x8 t8;
            #pragma unroll
            for (int i = 0; i < 4; ++i) {
                const float* row = &tl[(kg * 16 + quad * 4 + i) * 132 + dp * 32 + n];
                t8[i]     = (_Float16)row[0];
                t8[4 + i] = (_Float16)row[16];
            }
            const int v = (b * 64 + kt * 2 + kg) * 4 + dp;
            *(f16x8*)(Vt + (size_t)v * 512 + lane * 8) = t8;
        }
    }
}

// ---------------------------------------------------------------------------
// Attention v9: r5 skeleton (4 waves x 16 rows, all waves every chunk,
// depth-2 counted-vmcnt) with a SHORTER SERIAL CHAIN (the round-9 change).
// r8 post-mortem: direct counters — MfmaUtil 11.5%, VALUBusy 21.7%,
// Occupancy 11% -> latency-bound. r6/r7 nulls + r8 explain the binder:
// makespan = per-block serial chain = nch x (barrier + vmcnt + ds_read +
// MFMA + exp2); tail blocks (nch=16) run solo on their CU, phases sum.
// v9 shortens the chain two ways:
//  1. KVBLK 64 -> 128: nch_max 16 -> 8. Half the barrier/vmcnt instances;
//     2x fatter phases so pipes overlap within a phase.
//  2. V DIRECT-TO-REG (r0's proven per-lane fragment loads): bufV dropped;
//     LDS = 2 x 32KB K only (64KB, 2 blocks/CU unchanged). Per-wave LDS
//     reads halve; V rides the VMEM pipe, prefetched under QK^T, no
//     barrier involvement. PV (kpos-tile, dp) order identical to r5 ->
//     same o summation order.
// Mask safety at 128 granularity: K fragments in [64*ceil(vl/64),
// 128*ceil(vl/128)) may be poison -> st garbage -> e=exp2(garbage) is
// overridden to emaskval BEFORE any use (lrun add, pA store). V fragments
// are real on the whole 128-chunk range (prep's widened V-skip) -> no
// 0 x inf NaN path. vl==0: emaskval=1, all K poison overridden, V real.
// Pipeline: prologue stages chunks 0+1 (always within the 8-chunk
// allocation); per iter wait vmcnt(8) (chunk t's 8 K-loads landed, t+1's
// 8 still flying; compiler-inserted waits for V loads are tracked
// statically and compose), barrier (a) = t visible to all waves, compute,
// barrier (b) = buf[t&1] free, STAGE(t+2).
// Register rule: never index a register array with a runtime value (buf
// index t&1 is LDS memory, fine; all o/pA/qf indices compile-time).
// Transposed-S trick unchanged: S^T = K.Q^T C-layout == A-operand layout
// of 16x16x16 f16 MFMA -> exp2(S^T) feeds PV directly.
// ---------------------------------------------------------------------------
__global__ __launch_bounds__(256)
void attn_fwd(const float* __restrict__ Q, const unsigned short* __restrict__ Kb,
              const _Float16* __restrict__ Vt, const int* __restrict__ VL,
              float* __restrict__ O)
{
    __shared__ __align__(16) unsigned short bufK[2][32 * 512];  // 32 KB / buf

    const int tid  = threadIdx.x;
    const int lane = tid & 63;
    const int w    = tid >> 6;     // wave id == qtile id (16 q-rows each)
    const int quad = lane >> 4;
    const int m16  = lane & 15;

    const int idx = blockIdx.x;
    const int qg  = (idx >> 5) & 15;
    const int b   = (idx & 7) | ((((idx >> 3) + (idx >> 8)) & 3) << 3);
    const int q0  = qg * 64;

    const int vl  = VL[b];
    const int nch = (vl > 0) ? ((vl + 127) >> 7) : 8;   // 128-kpos chunks
    const float emaskval = (vl == 0) ? 1.0f : 0.0f;

    // Q fragments for this wave's qtile (B-operand of transposed QK^T)
    s16x8 qf[4];
    {
        const float* qrow = Q + ((size_t)b * LQ + q0 + w * 16 + m16) * DH + quad * 8;
        #pragma unroll
        for (int s = 0; s < 4; ++s) {
            const float4 a = *(const float4*)(qrow + s * 32);
            const float4 c = *(const float4*)(qrow + s * 32 + 4);
            union { s16x8 v; unsigned short u[8]; } t;
            t.u[0] = f2bf(a.x); t.u[1] = f2bf(a.y); t.u[2] = f2bf(a.z); t.u[3] = f2bf(a.w);
            t.u[4] = f2bf(c.x); t.u[5] = f2bf(c.y); t.u[6] = f2bf(c.z); t.u[7] = f2bf(c.w);
            qf[s] = t.v;
        }
    }

    f32x4 o[8];
    #pragma unroll
    for (int dt = 0; dt < 8; ++dt) o[dt] = (f32x4){0.f, 0.f, 0.f, 0.f};
    float lrun = 0.f;

    // 128-kpos chunk t: K shorts [t*16384, (t+1)*16384); V fragment-pairs
    // at 16-tile index t*8+g. kg0 wave-uniform (DMA); vb per-lane (direct).
    const unsigned short* kg0 = Kb + (size_t)b * (256 * 512);
    const _Float16*       vb  = Vt + (size_t)b * (256 * 512) + lane * 8;
    const int co = tid * 8;  // this thread's 16B slot within a 32KB K copy

    // STAGE(c, t): 8 x global_load_lds dwordx4 per thread (K only)
    //              = 8 vmcnt events per wave
#define STAGE(c, t)                                                             \
    do {                                                                        \
        const unsigned short* gk_ = kg0 + (size_t)(t) * 16384;                  \
        _Pragma("unroll")                                                       \
        for (int it_ = 0; it_ < 8; ++it_)                                       \
            G2L16(gk_ + it_ * 2048 + co, &bufK[c][it_ * 2048 + co]);            \
    } while (0)

    // prologue: stage chunks 0 and 1 (chunk 1 always within the 8-chunk
    // batch allocation; unused/poison bytes are never computed if nch==1)
    STAGE(0, 0);
    STAGE(1, 1);

    for (int t = 0; t < nch; ++t) {
        // wait for chunk t's K to land: only chunk t+1's 8 per-wave loads
        // may remain in flight. Last iteration: drain everything.
        if (t + 1 < nch) { asm volatile("s_waitcnt vmcnt(8)" ::: "memory"); }
        else             { asm volatile("s_waitcnt vmcnt(0)" ::: "memory"); }
        __builtin_amdgcn_sched_barrier(0);
        __builtin_amdgcn_s_barrier();          // (a) chunk t visible to all waves
        __builtin_amdgcn_sched_barrier(0);

        const unsigned short* bk = &bufK[t & 1][0];
        const bool maskc = (t * 128 + 128 > vl);
        f16x4 pA[8];

        // ---- S^T = K Q^T per 16-kpos tile g (8 tiles), softmaxed now ----
        #pragma unroll
        for (int g = 0; g < 8; ++g) {
            f32x4 st = (f32x4){0.f, 0.f, 0.f, 0.f};
            #pragma unroll
            for (int s = 0; s < 4; ++s) {
                const s16x8 kf = *(const s16x8*)(bk + (g * 4 + s) * 512 + lane * 8);
                st = __builtin_amdgcn_mfma_f32_16x16x32_bf16(kf, qf[s], st, 0, 0, 0);
            }
            #pragma unroll
            for (int i = 0; i < 4; ++i) {
                float e = __builtin_amdgcn_exp2f(st[i] * ESCALE);
                if (maskc && (t * 128 + g * 16 + quad * 4 + i >= vl)) e = emaskval;
                lrun += e;
                pA[g][i] = (_Float16)e;
            }
        }

        // ---- O += P V : 8 kpos-tiles x 4 d-pairs, V direct from global ----
        #pragma unroll
        for (int g = 0; g < 8; ++g) {
            const _Float16* vc = vb + (size_t)((t * 8 + g) * 4) * 512;
            #pragma unroll
            for (int dp = 0; dp < 4; ++dp) {
                const f16x8 w8 = *(const f16x8*)(vc + dp * 512);
                const f16x4 lo = __builtin_shufflevector(w8, w8, 0, 1, 2, 3);
                const f16x4 hi = __builtin_shufflevector(w8, w8, 4, 5, 6, 7);
                o[dp * 2]     = __builtin_amdgcn_mfma_f32_16x16x16f16(pA[g], lo, o[dp * 2],     0, 0, 0);
                o[dp * 2 + 1] = __builtin_amdgcn_mfma_f32_16x16x16f16(pA[g], hi, o[dp * 2 + 1], 0, 0, 0);
            }
        }

        __builtin_amdgcn_s_barrier();          // (b) all waves done reading buf[t&1]
        __builtin_amdgcn_sched_barrier(0);
        if (t + 2 < nch) STAGE(t & 1, t + 2);  // overwrite the vacated buffer
    }
#undef STAGE

    // ---- epilogue: no split-K merge; wave owns its 16 rows outright ----
    float L = lrun;
    L += __shfl_xor(L, 16);
    L += __shfl_xor(L, 32);
    const size_t obase = ((size_t)b * LQ + q0 + w * 16 + quad * 4) * DH + m16;
    #pragma unroll
    for (int r = 0; r < 4; ++r) {
        const float inv = 1.0f / __shfl(L, quad * 4 + r);
        #pragma unroll
        for (int dt = 0; dt < 8; ++dt)
            O[obase + (size_t)r * DH + dt * 16] = o[dt][r] * inv;
    }
}

extern "C" void kernel_launch(void* const* d_in, const int* in_sizes, int n_in,
                              void* d_out, int out_size, void* d_ws, size_t ws_size,
                              hipStream_t stream) {
    const float* Q  = (const float*)d_in[0];
    const float* K  = (const float*)d_in[1];
    const float* V  = (const float*)d_in[2];
    const int*   VL = (const int*)d_in[3];
    float* O = (float*)d_out;
    (void)in_sizes; (void)n_in; (void)out_size; (void)ws_size;

    unsigned short* Kb = (unsigned short*)d_ws;                      // 8 MB K fragments
    _Float16*       Vt = (_Float16*)(Kb + (size_t)B_N * 256 * 512);  // 8 MB V frag-pairs

    prep_kv<<<dim3(2048), dim3(256), 0, stream>>>(K, V, VL, Kb, Vt);
    attn_fwd<<<dim3(B_N * (LQ / 64)), dim3(256), 0, stream>>>(Q, Kb, Vt, VL, O);
}

// Round 11
// 116.433 us; speedup vs baseline: 1.0839x; 1.0053x over previous
//
#include <hip/hip_runtime.h>

#define B_N 32
#define LQ  1024
#define LK  1024
#define DH  128

typedef __attribute__((ext_vector_type(4))) float    f32x4;
typedef __attribute__((ext_vector_type(8))) short    s16x8;
typedef __attribute__((ext_vector_type(4))) _Float16 f16x4;
typedef __attribute__((ext_vector_type(8))) _Float16 f16x8;

// fp32 -> bf16 round-to-nearest-even
__device__ inline unsigned short f2bf(float f) {
    union { float f; unsigned u; } c; c.f = f;
    unsigned u = c.u;
    u += 0x7fffu + ((u >> 16) & 1u);
    return (unsigned short)(u >> 16);
}

// logit2 = score * (1/sqrt(128)) * log2(e)
#define ESCALE 0.12751743f

// async global->LDS, 16B per lane (dest must be wave-uniform base + lane*16)
#define G2L16(gp, lp) __builtin_amdgcn_global_load_lds(                         \
    (const __attribute__((address_space(1))) void*)(gp),                        \
    (__attribute__((address_space(3))) void*)(lp), 16, 0, 0)

// ---------------------------------------------------------------------------
// Prepass: byte-identical to r5 (the best round). V-skip at 64-kpos
// granularity — matches attn v11's V usage exactly (V tiles touched:
// kt < 2*nch with nch=ceil(vl/64); vl==0 -> all 32 real, needed for the
// uniform-softmax path). K-skip unchanged.
// blocks 0..1023: K tiles -> Kb bf16 fragments for QK^T (16x16x32).
// blocks 1024..2047: V tiles -> Vt f16 fragment-PAIRS for PV (16x16x16).
// ---------------------------------------------------------------------------
__global__ __launch_bounds__(256)
void prep_kv(const float* __restrict__ K, const float* __restrict__ V,
             const int* __restrict__ VL,
             unsigned short* __restrict__ Kb, _Float16* __restrict__ Vt)
{
    __shared__ float tl[32 * 132];
    const int tid  = threadIdx.x;
    const int lane = tid & 63;
    const int wv   = tid >> 6;
    const int n    = lane & 15;
    const int quad = lane >> 4;

    const int  idx = blockIdx.x;
    const bool isK = (idx >> 10) == 0;
    const int  b   = (idx & 7) | (((idx >> 3) & 3) << 3);
    const int  kt  = (idx >> 5) & 31;

    const int vl = VL[b];
    if (isK) {
        if (vl <= 0 || kt >= 2 * ((vl + 63) >> 6)) return;   // block-uniform
    } else {
        const int nch = (vl > 0) ? ((vl + 63) >> 6) : 16;
        if (kt >= 2 * nch) return;                           // block-uniform
    }

    const float4* src = (const float4*)((isK ? K : V) + ((size_t)b * LK + kt * 32) * DH);
    #pragma unroll
    for (int h = 0; h < 4; ++h) {
        const int i2 = h * 256 + tid;
        const int row = i2 >> 5, c4 = i2 & 31;
        *(float4*)&tl[row * 132 + c4 * 4] = src[i2];
    }
    __syncthreads();

    if (isK) {
        union { s16x8 v; unsigned short u[8]; } t8;
        #pragma unroll
        for (int h = 0; h < 2; ++h) {
            const int f = wv * 2 + h;
            const int tt2 = f >> 2, s = f & 3;
            const float* p = &tl[(tt2 * 16 + n) * 132 + s * 32 + quad * 8];
            const float4 a = *(const float4*)p;
            const float4 c = *(const float4*)(p + 4);
            t8.u[0] = f2bf(a.x); t8.u[1] = f2bf(a.y); t8.u[2] = f2bf(a.z); t8.u[3] = f2bf(a.w);
            t8.u[4] = f2bf(c.x); t8.u[5] = f2bf(c.y); t8.u[6] = f2bf(c.z); t8.u[7] = f2bf(c.w);
            const int w = b * 256 + (kt * 2 + tt2) * 4 + s;
            *(s16x8*)(Kb + (size_t)w * 512 + lane * 8) = t8.v;
        }
    } else {
        #pragma unroll
        for (int h = 0; h < 2; ++h) {
            const int f  = wv * 2 + h;
            const int kg = f >> 2, dp = f & 3;
            f16x8 t8;
            #pragma unroll
            for (int i = 0; i < 4; ++i) {
                const float* row = &tl[(kg * 16 + quad * 4 + i) * 132 + dp * 32 + n];
                t8[i]     = (_Float16)row[0];
                t8[4 + i] = (_Float16)row[16];
            }
            const int v = (b * 64 + kt * 2 + kg) * 4 + dp;
            *(f16x8*)(Vt + (size_t)v * 512 + lane * 8) = t8;
        }
    }
}

// ---------------------------------------------------------------------------
// Attention v11 = v10 with the LDS SIZE BUG FIXED (the only change).
// r10 post-mortem: bufK was declared [2][8*512] = 8 KB/buffer but a
// 64-kpos K chunk is 64 rows x 128 dh x 2B = 16 KB = 8192 shorts; STAGE
// (it_ up to 7, offsets to short 8191) overwrote buffer 1 with buffer 0's
// data and wrote past the array -> double-buffer corruption, absmax 1.18.
// Correct size: [2][16*512]. Theory under test (unchanged from r10):
// r8 counters (MfmaUtil 11.5%, VALUBusy 21.7%, Occ 11% — all pipes idle =
// latency-bound) + r6 (2x KV traffic ~ free) + all prior variants capped
// at 2 blocks/CU by 64KB LDS -> the binder is TOO FEW INDEPENDENT CHAINS
// per CU. v11: blocks of 2 waves x 16 rows (32 q-rows), KVBLK=64, K-only
// double-buffer (2 x 16 KB = 32 KB -> 5 blocks/CU capacity), V DIRECT-TO-
// REG (r0-proven fragment path), grid 1024 (2x traffic = proven free) ->
// ~4-5 resident blocks/CU, ~10 waves/CU, independent pipelined chains
// hiding each other's barrier/vmcnt stalls + backfill for the nch=16 tail.
// Pipeline (r5, kept): prologue stages chunks 0+1; per iter wait vmcnt(8)
// (chunk t's 8 per-wave K-loads landed, t+1's flying; compiler-inserted
// V-load waits drain older STAGE loads — conservative, never unsafe),
// barrier (a), compute, barrier (b), STAGE(t+2) into the vacated buffer.
// Register rule: never index a register array with a runtime value (buf
// index t&1 is LDS memory, fine; all o/pA/qf indices compile-time).
// Block swizzle: b low3 = idx&7, top2 mixes (idx>>3)+(idx>>8) — bijective
// (qg = bits 5-9 fixed => b bijective in bits 0-4); XCD-affine per batch.
// Transposed-S trick unchanged: S^T = K.Q^T C-layout == A-operand layout
// of 16x16x16 f16 MFMA -> exp2(S^T) feeds PV directly.
// ---------------------------------------------------------------------------
__global__ __launch_bounds__(128)
void attn_fwd(const float* __restrict__ Q, const unsigned short* __restrict__ Kb,
              const _Float16* __restrict__ Vt, const int* __restrict__ VL,
              float* __restrict__ O)
{
    __shared__ __align__(16) unsigned short bufK[2][16 * 512];  // 16 KB / buf

    const int tid  = threadIdx.x;
    const int lane = tid & 63;
    const int w    = tid >> 6;     // wave id == qtile id (16 q-rows each)
    const int quad = lane >> 4;
    const int m16  = lane & 15;

    const int idx = blockIdx.x;
    const int qg  = (idx >> 5) & 31;            // 32 q-groups of 32 rows
    const int b   = (idx & 7) | ((((idx >> 3) + (idx >> 8)) & 3) << 3);
    const int q0  = qg * 32;

    const int vl  = VL[b];
    const int nch = (vl > 0) ? ((vl + 63) >> 6) : 16;
    const float emaskval = (vl == 0) ? 1.0f : 0.0f;

    // Q fragments for this wave's qtile (B-operand of transposed QK^T)
    s16x8 qf[4];
    {
        const float* qrow = Q + ((size_t)b * LQ + q0 + w * 16 + m16) * DH + quad * 8;
        #pragma unroll
        for (int s = 0; s < 4; ++s) {
            const float4 a = *(const float4*)(qrow + s * 32);
            const float4 c = *(const float4*)(qrow + s * 32 + 4);
            union { s16x8 v; unsigned short u[8]; } t;
            t.u[0] = f2bf(a.x); t.u[1] = f2bf(a.y); t.u[2] = f2bf(a.z); t.u[3] = f2bf(a.w);
            t.u[4] = f2bf(c.x); t.u[5] = f2bf(c.y); t.u[6] = f2bf(c.z); t.u[7] = f2bf(c.w);
            qf[s] = t.v;
        }
    }

    f32x4 o[8];
    #pragma unroll
    for (int dt = 0; dt < 8; ++dt) o[dt] = (f32x4){0.f, 0.f, 0.f, 0.f};
    float lrun = 0.f;

    // 64-kpos chunk t: K shorts [t*8192, (t+1)*8192). V fragment-pairs at
    // 16-tile index t*4+g, per-lane direct (r0's proven vbase pattern).
    const unsigned short* kg0 = Kb + (size_t)b * (256 * 512);
    const _Float16*       vb  = Vt + (size_t)b * (256 * 512) + lane * 8;
    const int co = tid * 8;  // 16B slot: 128 thr x 8 iters x 16B = 16 KB

    // STAGE(c, t): 8 x global_load_lds dwordx4 per thread (K only)
    //              = 8 vmcnt events per wave
#define STAGE(c, t)                                                             \
    do {                                                                        \
        const unsigned short* gk_ = kg0 + (size_t)(t) * 8192;                   \
        _Pragma("unroll")                                                       \
        for (int it_ = 0; it_ < 8; ++it_)                                       \
            G2L16(gk_ + it_ * 1024 + co, &bufK[c][it_ * 1024 + co]);            \
    } while (0)

    // prologue: stage chunks 0 and 1 (chunk 1 always within the 16-chunk
    // batch allocation; unused/poison bytes are never computed if nch==1)
    STAGE(0, 0);
    STAGE(1, 1);

    for (int t = 0; t < nch; ++t) {
        // wait for chunk t's K to land: only chunk t+1's 8 per-wave loads
        // may remain in flight. Last iteration: drain everything.
        if (t + 1 < nch) { asm volatile("s_waitcnt vmcnt(8)" ::: "memory"); }
        else             { asm volatile("s_waitcnt vmcnt(0)" ::: "memory"); }
        __builtin_amdgcn_sched_barrier(0);
        __builtin_amdgcn_s_barrier();          // (a) chunk t visible to both waves
        __builtin_amdgcn_sched_barrier(0);

        const unsigned short* bk = &bufK[t & 1][0];
        const bool maskc = (t * 64 + 64 > vl);
        f16x4 pA[4];

        // ---- S^T = K Q^T per 16-kpos tile g, softmaxed immediately ----
        #pragma unroll
        for (int g = 0; g < 4; ++g) {
            f32x4 st = (f32x4){0.f, 0.f, 0.f, 0.f};
            #pragma unroll
            for (int s = 0; s < 4; ++s) {
                const s16x8 kf = *(const s16x8*)(bk + (g * 4 + s) * 512 + lane * 8);
                st = __builtin_amdgcn_mfma_f32_16x16x32_bf16(kf, qf[s], st, 0, 0, 0);
            }
            #pragma unroll
            for (int i = 0; i < 4; ++i) {
                float e = __builtin_amdgcn_exp2f(st[i] * ESCALE);
                if (maskc && (t * 64 + g * 16 + quad * 4 + i >= vl)) e = emaskval;
                lrun += e;
                pA[g][i] = (_Float16)e;
            }
        }

        // ---- O += P V : 4 kpos-tiles x 4 d-pairs, V direct from global ----
        #pragma unroll
        for (int g = 0; g < 4; ++g) {
            const _Float16* vc = vb + (size_t)((t * 4 + g) * 4) * 512;
            #pragma unroll
            for (int dp = 0; dp < 4; ++dp) {
                const f16x8 w8 = *(const f16x8*)(vc + dp * 512);
                const f16x4 lo = __builtin_shufflevector(w8, w8, 0, 1, 2, 3);
                const f16x4 hi = __builtin_shufflevector(w8, w8, 4, 5, 6, 7);
                o[dp * 2]     = __builtin_amdgcn_mfma_f32_16x16x16f16(pA[g], lo, o[dp * 2],     0, 0, 0);
                o[dp * 2 + 1] = __builtin_amdgcn_mfma_f32_16x16x16f16(pA[g], hi, o[dp * 2 + 1], 0, 0, 0);
            }
        }

        __builtin_amdgcn_s_barrier();          // (b) both waves done reading buf[t&1]
        __builtin_amdgcn_sched_barrier(0);
        if (t + 2 < nch) STAGE(t & 1, t + 2);  // overwrite the vacated buffer
    }
#undef STAGE

    // ---- epilogue: wave owns its 16 rows outright ----
    float L = lrun;
    L += __shfl_xor(L, 16);
    L += __shfl_xor(L, 32);
    const size_t obase = ((size_t)b * LQ + q0 + w * 16 + quad * 4) * DH + m16;
    #pragma unroll
    for (int r = 0; r < 4; ++r) {
        const float inv = 1.0f / __shfl(L, quad * 4 + r);
        #pragma unroll
        for (int dt = 0; dt < 8; ++dt)
            O[obase + (size_t)r * DH + dt * 16] = o[dt][r] * inv;
    }
}

extern "C" void kernel_launch(void* const* d_in, const int* in_sizes, int n_in,
                              void* d_out, int out_size, void* d_ws, size_t ws_size,
                              hipStream_t stream) {
    const float* Q  = (const float*)d_in[0];
    const float* K  = (const float*)d_in[1];
    const float* V  = (const float*)d_in[2];
    const int*   VL = (const int*)d_in[3];
    float* O = (float*)d_out;
    (void)in_sizes; (void)n_in; (void)out_size; (void)ws_size;

    unsigned short* Kb = (unsigned short*)d_ws;                      // 8 MB K fragments
    _Float16*       Vt = (_Float16*)(Kb + (size_t)B_N * 256 * 512);  // 8 MB V frag-pairs

    prep_kv<<<dim3(2048), dim3(256), 0, stream>>>(K, V, VL, Kb, Vt);
    attn_fwd<<<dim3(B_N * (LQ / 32)), dim3(128), 0, stream>>>(Q, Kb, Vt, VL, O);
}

// Round 12
// 114.016 us; speedup vs baseline: 1.1069x; 1.0212x over previous
//
#include <hip/hip_runtime.h>

#define B_N 32
#define LQ  1024
#define LK  1024
#define DH  128

typedef __attribute__((ext_vector_type(4))) float    f32x4;
typedef __attribute__((ext_vector_type(8))) short    s16x8;
typedef __attribute__((ext_vector_type(4))) _Float16 f16x4;
typedef __attribute__((ext_vector_type(8))) _Float16 f16x8;

// fp32 -> bf16 round-to-nearest-even
__device__ inline unsigned short f2bf(float f) {
    union { float f; unsigned u; } c; c.f = f;
    unsigned u = c.u;
    u += 0x7fffu + ((u >> 16) & 1u);
    return (unsigned short)(u >> 16);
}

// logit2 = score * (1/sqrt(128)) * log2(e)
#define ESCALE 0.12751743f

// async global->LDS, 16B per lane (dest must be wave-uniform base + lane*16)
#define G2L16(gp, lp) __builtin_amdgcn_global_load_lds(                         \
    (const __attribute__((address_space(1))) void*)(gp),                        \
    (__attribute__((address_space(3))) void*)(lp), 16, 0, 0)

// ---------------------------------------------------------------------------
// FINAL (r12 = r5 verbatim, the best-measured variant: 113.85 us).
// 11-round ledger: traffic 0.5x/2x (r2/r6), XCD locality (r3), LDS
// amplification 0.5x/0.25x (r4/r8), counted-vmcnt pipeline (r5, best),
// LPT + pairing balance (r6/r7), KVBLK=128 (r9), 4 co-resident chains +
// V-direct (r11) — all within +/-3 us of this kernel. attn is latency-
// bound (r8 counters: MfmaUtil 11.5%, VALUBusy 21.7%, Occ 11%) at a floor
// invariant to the whole decomposition space; the measured window is
// dominated by ~84 us of harness 256MiB poison-fills at 79-80% HBM peak
// (their roofline) + ~7 us HBM-bound prep.
//
// Prepass: vl-aware skip (~46% of tiles never read by attn).
// blocks 0..1023: K tiles -> Kb bf16 fragments for QK^T (16x16x32).
// blocks 1024..2047: V tiles -> Vt f16 fragment-PAIRS for PV (16x16x16).
// XCD-aligned decode (neutral, kept): idx&7 == b&7 matches attn's swizzle.
// ---------------------------------------------------------------------------
__global__ __launch_bounds__(256)
void prep_kv(const float* __restrict__ K, const float* __restrict__ V,
             const int* __restrict__ VL,
             unsigned short* __restrict__ Kb, _Float16* __restrict__ Vt)
{
    __shared__ float tl[32 * 132];
    const int tid  = threadIdx.x;
    const int lane = tid & 63;
    const int wv   = tid >> 6;
    const int n    = lane & 15;
    const int quad = lane >> 4;

    const int  idx = blockIdx.x;
    const bool isK = (idx >> 10) == 0;
    const int  b   = (idx & 7) | (((idx >> 3) & 3) << 3);
    const int  kt  = (idx >> 5) & 31;

    const int vl = VL[b];
    if (isK) {
        if (vl <= 0 || kt >= 2 * ((vl + 63) >> 6)) return;   // block-uniform
    } else {
        const int nch = (vl > 0) ? ((vl + 63) >> 6) : 16;
        if (kt >= 2 * nch) return;                           // block-uniform
    }

    const float4* src = (const float4*)((isK ? K : V) + ((size_t)b * LK + kt * 32) * DH);
    #pragma unroll
    for (int h = 0; h < 4; ++h) {
        const int i2 = h * 256 + tid;
        const int row = i2 >> 5, c4 = i2 & 31;
        *(float4*)&tl[row * 132 + c4 * 4] = src[i2];
    }
    __syncthreads();

    if (isK) {
        union { s16x8 v; unsigned short u[8]; } t8;
        #pragma unroll
        for (int h = 0; h < 2; ++h) {
            const int f = wv * 2 + h;
            const int tt2 = f >> 2, s = f & 3;
            const float* p = &tl[(tt2 * 16 + n) * 132 + s * 32 + quad * 8];
            const float4 a = *(const float4*)p;
            const float4 c = *(const float4*)(p + 4);
            t8.u[0] = f2bf(a.x); t8.u[1] = f2bf(a.y); t8.u[2] = f2bf(a.z); t8.u[3] = f2bf(a.w);
            t8.u[4] = f2bf(c.x); t8.u[5] = f2bf(c.y); t8.u[6] = f2bf(c.z); t8.u[7] = f2bf(c.w);
            const int w = b * 256 + (kt * 2 + tt2) * 4 + s;
            *(s16x8*)(Kb + (size_t)w * 512 + lane * 8) = t8.v;
        }
    } else {
        #pragma unroll
        for (int h = 0; h < 2; ++h) {
            const int f  = wv * 2 + h;
            const int kg = f >> 2, dp = f & 3;
            f16x8 t8;
            #pragma unroll
            for (int i = 0; i < 4; ++i) {
                const float* row = &tl[(kg * 16 + quad * 4 + i) * 132 + dp * 32 + n];
                t8[i]     = (_Float16)row[0];
                t8[4 + i] = (_Float16)row[16];
            }
            const int v = (b * 64 + kt * 2 + kg) * 4 + dp;
            *(f16x8*)(Vt + (size_t)v * 512 + lane * 8) = t8;
        }
    }
}

// ---------------------------------------------------------------------------
// Attention (r5 structure): 4 waves x 16 q-rows, 64-row block, K+V LDS
// double-buffer, DEPTH-2 COUNTED-VMCNT pipeline (guide T4).
// Pipeline: prologue stages chunks 0+1; per iter wait vmcnt(8) (chunk t
// landed, t+1's 8 per-wave loads still flying), barrier (a) = t visible
// to all waves, compute t, barrier (b) = buf[t&1] free, STAGE(t+2) into
// it. Last iteration drains vmcnt(0).
// LDS 64KB -> 2 blocks/CU, 8 waves/CU. Register rule: never index a
// register array with a runtime value (buf index t&1 is LDS memory, fine).
// Block swizzle: b low3 = idx&7 (XCD-affine per batch), top2 mixes
// (idx>>3)+(idx>>8); bijective per 32-block group (qg untouched).
// Transposed-S trick: S^T = K.Q^T C-layout == A-operand layout of
// 16x16x16 f16 MFMA -> exp2(S^T) feeds PV directly.
// ---------------------------------------------------------------------------
__global__ __launch_bounds__(256)
void attn_fwd(const float* __restrict__ Q, const unsigned short* __restrict__ Kb,
              const _Float16* __restrict__ Vt, const int* __restrict__ VL,
              float* __restrict__ O)
{
    __shared__ __align__(16) unsigned short bufK[2][16 * 512];  // 16 KB / buf
    __shared__ __align__(16) _Float16       bufV[2][16 * 512];  // 16 KB / buf

    const int tid  = threadIdx.x;
    const int lane = tid & 63;
    const int w    = tid >> 6;     // wave id == qtile id (16 q-rows each)
    const int quad = lane >> 4;
    const int m16  = lane & 15;

    const int idx = blockIdx.x;
    const int qg  = (idx >> 5) & 15;
    const int b   = (idx & 7) | ((((idx >> 3) + (idx >> 8)) & 3) << 3);
    const int q0  = qg * 64;

    const int vl  = VL[b];
    const int nch = (vl > 0) ? ((vl + 63) >> 6) : 16;
    const float emaskval = (vl == 0) ? 1.0f : 0.0f;

    // Q fragments for this wave's qtile (B-operand of transposed QK^T)
    s16x8 qf[4];
    {
        const float* qrow = Q + ((size_t)b * LQ + q0 + w * 16 + m16) * DH + quad * 8;
        #pragma unroll
        for (int s = 0; s < 4; ++s) {
            const float4 a = *(const float4*)(qrow + s * 32);
            const float4 c = *(const float4*)(qrow + s * 32 + 4);
            union { s16x8 v; unsigned short u[8]; } t;
            t.u[0] = f2bf(a.x); t.u[1] = f2bf(a.y); t.u[2] = f2bf(a.z); t.u[3] = f2bf(a.w);
            t.u[4] = f2bf(c.x); t.u[5] = f2bf(c.y); t.u[6] = f2bf(c.z); t.u[7] = f2bf(c.w);
            qf[s] = t.v;
        }
    }

    f32x4 o[8];
    #pragma unroll
    for (int dt = 0; dt < 8; ++dt) o[dt] = (f32x4){0.f, 0.f, 0.f, 0.f};
    float lrun = 0.f;

    // chunk t occupies shorts [t*8192, (t+1)*8192) of this batch's Kb / Vt
    const unsigned short* kg0 = Kb + (size_t)b * (256 * 512);
    const _Float16*       vg0 = Vt + (size_t)b * (256 * 512);
    const int co = tid * 8;  // this thread's 16B slot within a 16KB chunk copy

    // STAGE(c, t): 8 x global_load_lds dwordx4 per thread (4 K + 4 V)
    //              = 8 vmcnt events per wave
#define STAGE(c, t)                                                             \
    do {                                                                        \
        const unsigned short* gk_ = kg0 + (size_t)(t) * 8192;                   \
        const _Float16*       gv_ = vg0 + (size_t)(t) * 8192;                   \
        _Pragma("unroll")                                                       \
        for (int it_ = 0; it_ < 4; ++it_)                                       \
            G2L16(gk_ + it_ * 2048 + co, &bufK[c][it_ * 2048 + co]);            \
        _Pragma("unroll")                                                       \
        for (int it_ = 0; it_ < 4; ++it_)                                       \
            G2L16(gv_ + it_ * 2048 + co, &bufV[c][it_ * 2048 + co]);            \
    } while (0)

    // prologue: stage chunks 0 and 1 (chunk 1 is always within the batch's
    // 16-chunk allocation; unused/poison bytes are never computed if nch==1)
    STAGE(0, 0);
    STAGE(1, 1);

    for (int t = 0; t < nch; ++t) {
        // wait for chunk t to land: only chunk t+1's 8 per-wave loads may
        // remain in flight. Last iteration: drain everything.
        if (t + 1 < nch) { asm volatile("s_waitcnt vmcnt(8)" ::: "memory"); }
        else             { asm volatile("s_waitcnt vmcnt(0)" ::: "memory"); }
        __builtin_amdgcn_sched_barrier(0);
        __builtin_amdgcn_s_barrier();          // (a) chunk t visible to all waves
        __builtin_amdgcn_sched_barrier(0);

        const unsigned short* bk = &bufK[t & 1][0];
        const _Float16*       bv = &bufV[t & 1][0];
        const bool maskc = (t * 64 + 64 > vl);
        f16x4 pA[4];

        // ---- S^T = K Q^T per 16-kpos tile g, softmaxed immediately ----
        #pragma unroll
        for (int g = 0; g < 4; ++g) {
            f32x4 st = (f32x4){0.f, 0.f, 0.f, 0.f};
            #pragma unroll
            for (int s = 0; s < 4; ++s) {
                const s16x8 kf = *(const s16x8*)(bk + (g * 4 + s) * 512 + lane * 8);
                st = __builtin_amdgcn_mfma_f32_16x16x32_bf16(kf, qf[s], st, 0, 0, 0);
            }
            #pragma unroll
            for (int i = 0; i < 4; ++i) {
                float e = __builtin_amdgcn_exp2f(st[i] * ESCALE);
                if (maskc && (t * 64 + g * 16 + quad * 4 + i >= vl)) e = emaskval;
                lrun += e;
                pA[g][i] = (_Float16)e;
            }
        }

        // ---- O += P V : 4 kpos-tiles x 4 d-pairs ----
        #pragma unroll
        for (int g = 0; g < 4; ++g) {
            #pragma unroll
            for (int dp = 0; dp < 4; ++dp) {
                const f16x8 w8 = *(const f16x8*)(bv + (g * 4 + dp) * 512 + lane * 8);
                const f16x4 lo = __builtin_shufflevector(w8, w8, 0, 1, 2, 3);
                const f16x4 hi = __builtin_shufflevector(w8, w8, 4, 5, 6, 7);
                o[dp * 2]     = __builtin_amdgcn_mfma_f32_16x16x16f16(pA[g], lo, o[dp * 2],     0, 0, 0);
                o[dp * 2 + 1] = __builtin_amdgcn_mfma_f32_16x16x16f16(pA[g], hi, o[dp * 2 + 1], 0, 0, 0);
            }
        }

        __builtin_amdgcn_s_barrier();          // (b) all waves done reading buf[t&1]
        __builtin_amdgcn_sched_barrier(0);
        if (t + 2 < nch) STAGE(t & 1, t + 2);  // overwrite the vacated buffer
    }
#undef STAGE

    // ---- epilogue: no split-K merge; wave owns its 16 rows outright ----
    float L = lrun;
    L += __shfl_xor(L, 16);
    L += __shfl_xor(L, 32);
    const size_t obase = ((size_t)b * LQ + q0 + w * 16 + quad * 4) * DH + m16;
    #pragma unroll
    for (int r = 0; r < 4; ++r) {
        const float inv = 1.0f / __shfl(L, quad * 4 + r);
        #pragma unroll
        for (int dt = 0; dt < 8; ++dt)
            O[obase + (size_t)r * DH + dt * 16] = o[dt][r] * inv;
    }
}

extern "C" void kernel_launch(void* const* d_in, const int* in_sizes, int n_in,
                              void* d_out, int out_size, void* d_ws, size_t ws_size,
                              hipStream_t stream) {
    const float* Q  = (const float*)d_in[0];
    const float* K  = (const float*)d_in[1];
    const float* V  = (const float*)d_in[2];
    const int*   VL = (const int*)d_in[3];
    float* O = (float*)d_out;
    (void)in_sizes; (void)n_in; (void)out_size; (void)ws_size;

    unsigned short* Kb = (unsigned short*)d_ws;                      // 8 MB K fragments
    _Float16*       Vt = (_Float16*)(Kb + (size_t)B_N * 256 * 512);  // 8 MB V frag-pairs

    prep_kv<<<dim3(2048), dim3(256), 0, stream>>>(K, V, VL, Kb, Vt);
    attn_fwd<<<dim3(B_N * (LQ / 64)), dim3(256), 0, stream>>>(Q, Kb, Vt, VL, O);
}